// Round 1
// baseline (77.527 us; speedup 1.0000x reference)
//
#include <hip/hip_runtime.h>
#include <cfloat>

#define NTHREADS 256
#define KCAP 64
#define CAP 2048

// Level geometry (compile-time)
//  l0: 128x128, stride 8,  HW=16384, flagbase 0
//  l1: 64x64,   stride 16, HW=4096,  flagbase 262144
//  l2: 32x32,   stride 32, HW=1024,  flagbase 327680
// flags total = 16*(16384+4096+1024) = 344064 bytes (uint8)
// partials: 3072 floats at byte offset 344064

__device__ __forceinline__ float seg_dist(float px, float py,
                                          float x1, float y1, float x2, float y2) {
    float vx = x2 - x1, vy = y2 - y1;
    float wx = px - x1, wy = py - y1;
    float vv = vx * vx + vy * vy + 1e-9f;
    float t = (wx * vx + wy * vy) / vv;
    t = fminf(fmaxf(t, 0.f), 1.f);
    float dx = px - (x1 + t * vx);
    float dy = py - (y1 + t * vy);
    return sqrtf(dx * dx + dy * dy + 1e-12f);
}

__device__ __forceinline__ float clip64(float v) {
    return fminf(fmaxf(v, -64.f), 64.f);
}

__global__ __launch_bounds__(NTHREADS)
void select_loss_kernel(const float* __restrict__ reg0, const float* __restrict__ cls0,
                        const float* __restrict__ reg1, const float* __restrict__ cls1,
                        const float* __restrict__ reg2, const float* __restrict__ cls2,
                        const float* __restrict__ gt,
                        unsigned char* __restrict__ flags,
                        float* __restrict__ partials) {
    int t = blockIdx.x;          // 0..3071
    int l = t >> 10;             // level
    int bg = t & 1023;
    int b = bg >> 6, g = bg & 63;

    int Ws, HW, flagbase; float stride;
    const float* reg; const float* cls;
    if (l == 0)      { Ws = 128; HW = 16384; stride = 8.f;  reg = reg0; cls = cls0; flagbase = 0; }
    else if (l == 1) { Ws = 64;  HW = 4096;  stride = 16.f; reg = reg1; cls = cls1; flagbase = 262144; }
    else             { Ws = 32;  HW = 1024;  stride = 32.f; reg = reg2; cls = cls2; flagbase = 327680; }
    int Hs = Ws;

    const float* G = gt + (size_t)((b * 64 + g) * 6);
    float Ax = G[0], Ay = G[1], Bx = G[2], By = G[3], Cx = G[4], Cy = G[5];

    __shared__ float sdist[CAP];
    __shared__ int   spix[CAP];
    __shared__ int   scount;
    __shared__ unsigned long long skey[NTHREADS];
    __shared__ float ssum[NTHREADS];
    __shared__ int   ssel[KCAP];
    __shared__ int   spos;

    int tid = threadIdx.x;
    if (tid == 0) scount = 0;
    __syncthreads();

    float inv_s = 1.f / stride;
    float xmn = fminf(Ax, fminf(Bx, Cx)) - 4.f;
    float xmx = fmaxf(Ax, fmaxf(Bx, Cx)) + 4.f;
    float ymn = fminf(Ay, fminf(By, Cy)) - 4.f;
    float ymx = fmaxf(Ay, fmaxf(By, Cy)) + 4.f;
    int w0 = max(0, (int)ceilf(xmn * inv_s - 0.5f));
    int w1 = min(Ws - 1, (int)floorf(xmx * inv_s - 0.5f));
    int h0 = max(0, (int)ceilf(ymn * inv_s - 0.5f));
    int h1 = min(Hs - 1, (int)floorf(ymx * inv_s - 0.5f));
    int bw = w1 - w0 + 1, bh = h1 - h0 + 1;
    int nb = (bw > 0 && bh > 0) ? bw * bh : 0;

    for (int i = tid; i < nb; i += NTHREADS) {
        int w = w0 + i % bw;
        int h = h0 + i / bw;
        float px = (w + 0.5f) * stride;
        float py = (h + 0.5f) * stride;
        float d1 = (px - Bx) * (Ay - By) - (Ax - Bx) * (py - By);
        float d2 = (px - Cx) * (By - Cy) - (Bx - Cx) * (py - Cy);
        float d3 = (px - Ax) * (Cy - Ay) - (Cx - Ax) * (py - Ay);
        bool hasneg = (d1 < 0.f) || (d2 < 0.f) || (d3 < 0.f);
        bool haspos = (d1 > 0.f) || (d2 > 0.f) || (d3 > 0.f);
        bool inside = !(hasneg && haspos);
        float dist = fminf(seg_dist(px, py, Ax, Ay, Bx, By),
                     fminf(seg_dist(px, py, Bx, By, Cx, Cy),
                           seg_dist(px, py, Cx, Cy, Ax, Ay)));
        if (inside || dist <= 3.0f) {
            int slot = atomicAdd(&scount, 1);
            if (slot < CAP) { sdist[slot] = dist; spix[slot] = h * Ws + w; }
        }
    }
    __syncthreads();
    int count = min(scount, CAP);

    int nsel;
    if (count <= KCAP) {
        nsel = count;
        if (tid < count) ssel[tid] = tid;
    } else {
        nsel = KCAP;
        for (int k = 0; k < KCAP; ++k) {
            unsigned long long best = ~0ULL;
            for (int i = tid; i < count; i += NTHREADS) {
                unsigned long long key =
                    ((unsigned long long)__float_as_uint(sdist[i]) << 32) | (unsigned)spix[i];
                if (key < best) best = key;
            }
            skey[tid] = best;
            __syncthreads();
            for (int s = NTHREADS / 2; s > 0; s >>= 1) {
                if (tid < s && skey[tid + s] < skey[tid]) skey[tid] = skey[tid + s];
                __syncthreads();
            }
            unsigned long long mk = skey[0];
            for (int i = tid; i < count; i += NTHREADS) {
                unsigned long long key =
                    ((unsigned long long)__float_as_uint(sdist[i]) << 32) | (unsigned)spix[i];
                if (key == mk) spos = i;   // unique writer (pix unique)
            }
            __syncthreads();
            if (tid == 0) { ssel[k] = spos; sdist[spos] = FLT_MAX; }
            __syncthreads();
        }
    }
    __syncthreads();

    float local = 0.f;
    for (int i = tid; i < nsel; i += NTHREADS) {
        int pix = spix[ssel[i]];
        int h = pix / Ws, w = pix - h * Ws;
        float ax = (w + 0.5f) * stride, ay = (h + 0.5f) * stride;
        float g0x = (Ax - ax) * inv_s, g0y = (Ay - ay) * inv_s;
        float g1x = (Bx - ax) * inv_s, g1y = (By - ay) * inv_s;
        float g2x = (Cx - ax) * inv_s, g2y = (Cy - ay) * inv_s;
        const float* rb = reg + (size_t)b * 6 * HW + pix;
        float p0x = clip64(rb[0]);
        float p0y = clip64(rb[HW]);
        float p1x = clip64(rb[2 * HW]);
        float p1y = clip64(rb[3 * HW]);
        float p2x = clip64(rb[4 * HW]);
        float p2y = clip64(rb[5 * HW]);
        float lp0 = (p0x - g0x) * (p0x - g0x) + (p0y - g0y) * (p0y - g0y);
        float d11 = sqrtf((p1x - g1x) * (p1x - g1x) + (p1y - g1y) * (p1y - g1y));
        float d12 = sqrtf((p1x - g2x) * (p1x - g2x) + (p1y - g2y) * (p1y - g2y));
        float d21 = sqrtf((p2x - g1x) * (p2x - g1x) + (p2y - g1y) * (p2y - g1y));
        float d22 = sqrtf((p2x - g2x) * (p2x - g2x) + (p2y - g2y) * (p2y - g2y));
        float cd = fminf(d11, d12) + fminf(d21, d22) + fminf(d11, d21) + fminf(d12, d22);
        float x = cls[(size_t)b * HW + pix];
        float clsl = fmaxf(-x, 0.f) + log1pf(expf(-fabsf(x)));   // -log_sigmoid(x)
        local += lp0 + cd + clsl;
        flags[flagbase + b * HW + pix] = 1;
    }
    ssum[tid] = local;
    __syncthreads();
    for (int s = NTHREADS / 2; s > 0; s >>= 1) {
        if (tid < s) ssum[tid] += ssum[tid + s];
        __syncthreads();
    }
    if (tid == 0) partials[t] = ssum[0];
}

__global__ __launch_bounds__(NTHREADS)
void finalize_kernel(const float* __restrict__ obj0, const float* __restrict__ obj1,
                     const float* __restrict__ obj2,
                     const unsigned char* __restrict__ flags,
                     const float* __restrict__ partials,
                     float* __restrict__ out) {
    const int N1 = 344064;     // obj cells
    const int N2 = 3072;       // partials
    float local = 0.f;
    for (int e = blockIdx.x * blockDim.x + threadIdx.x; e < N1 + N2;
         e += gridDim.x * blockDim.x) {
        if (e < N1) {
            const float* obj; int off;
            if (e < 262144)      { obj = obj0; off = e; }
            else if (e < 327680) { obj = obj1; off = e - 262144; }
            else                 { obj = obj2; off = e - 327680; }
            float x = obj[off];
            float lg = log1pf(expf(-fabsf(x)));
            float ls_pos = fminf(x, 0.f) - lg;     // log_sigmoid(x)
            float ls_neg = fminf(-x, 0.f) - lg;    // log_sigmoid(-x)
            float tt = (float)flags[e];
            local += -(1.2f * tt * ls_pos + (1.f - tt) * ls_neg);
        } else {
            local += partials[e - N1];
        }
    }
    __shared__ float ssum[NTHREADS];
    ssum[threadIdx.x] = local;
    __syncthreads();
    for (int s = NTHREADS / 2; s > 0; s >>= 1) {
        if (threadIdx.x < s) ssum[threadIdx.x] += ssum[threadIdx.x + s];
        __syncthreads();
    }
    if (threadIdx.x == 0) atomicAdd(out, ssum[0]);
}

extern "C" void kernel_launch(void* const* d_in, const int* in_sizes, int n_in,
                              void* d_out, int out_size, void* d_ws, size_t ws_size,
                              hipStream_t stream) {
    const float* reg0 = (const float*)d_in[0];
    const float* obj0 = (const float*)d_in[1];
    const float* cls0 = (const float*)d_in[2];
    const float* reg1 = (const float*)d_in[3];
    const float* obj1 = (const float*)d_in[4];
    const float* cls1 = (const float*)d_in[5];
    const float* reg2 = (const float*)d_in[6];
    const float* obj2 = (const float*)d_in[7];
    const float* cls2 = (const float*)d_in[8];
    const float* gt   = (const float*)d_in[9];

    unsigned char* flags = (unsigned char*)d_ws;
    float* partials = (float*)((char*)d_ws + 344064);

    hipMemsetAsync(d_ws, 0, 344064, stream);
    hipMemsetAsync(d_out, 0, sizeof(float), stream);

    select_loss_kernel<<<3072, NTHREADS, 0, stream>>>(
        reg0, cls0, reg1, cls1, reg2, cls2, gt, flags, partials);
    finalize_kernel<<<512, NTHREADS, 0, stream>>>(
        obj0, obj1, obj2, flags, partials, (float*)d_out);
}